// Round 8
// baseline (357.623 us; speedup 1.0000x reference)
//
#include <hip/hip_runtime.h>
#include <math.h>

#define TLEN   8192
#define BROWS  4096
#define NT     256
#define WPB    (NT / 64)        /* 4 waves per block, one row each */
#define GRID   (BROWS / WPB)    /* 1024 blocks */
#define TPW    1024             /* elems per wave-tile */
#define NTW    (TLEN / TPW)     /* 8 tiles per row */
#define SEG    16               /* elems per lane per tile (4 consecutive f4) */
#define GAMMA  0.99f
#define EPSN   1e-9

typedef float f4 __attribute__((ext_vector_type(4)));

// ---------------------------------------------------------------------------
// 1024-elem tile scan, lane l owns elems [16l, 16l+16).
// Rationale (round-6 post-mortem): __shfl = ds_bpermute, ~120cy latency, and
// the ~15-bpermute serial wave-scan chain (~1000+cy) ran once per 256 elems in
// all prior variants -> ~4cy/elem of pure cross-lane latency, serial per wave.
// Owning 16 consecutive elems per lane replaces 3/4 of that with a cheap
// serial fma compose (~2-4cy/step) and runs the wave-scan once per 1024 elems.
// ---------------------------------------------------------------------------
__device__ __forceinline__ void scan_tile16(const f4* R, const f4* D,
                                            const int lane, float& tc,
                                            float* __restrict__ dst,
                                            double& accS, double& accQ) {
  float rv[SEG], cv[SEG];
#pragma unroll
  for (int q = 0; q < 4; ++q) {
    rv[4 * q + 0] = R[q].x; rv[4 * q + 1] = R[q].y;
    rv[4 * q + 2] = R[q].z; rv[4 * q + 3] = R[q].w;
    cv[4 * q + 0] = fmaf(-GAMMA, D[q].x, GAMMA);
    cv[4 * q + 1] = fmaf(-GAMMA, D[q].y, GAMMA);
    cv[4 * q + 2] = fmaf(-GAMMA, D[q].z, GAMMA);
    cv[4 * q + 3] = fmaf(-GAMMA, D[q].w, GAMMA);
  }

  // local suffix scan of affine maps T_j(x) = rv + cv*x over the 16-segment
  float A = 0.f, P = 1.f;
#pragma unroll
  for (int j = SEG - 1; j >= 0; --j) {
    A = fmaf(cv[j], A, rv[j]);
    P *= cv[j];
    rv[j] = A;    // A_{[j, seg end)}
    cv[j] = P;    // P_{[j, seg end)}
  }

  // wave inclusive suffix scan of 64 segment composites (ONE per 1024 elems)
  float sA = A, sP = P;
#pragma unroll
  for (int dd = 1; dd < 64; dd <<= 1) {
    const float tA = __shfl_down(sA, dd);
    const float tP = __shfl_down(sP, dd);
    if (lane + dd < 64) { sA = fmaf(sP, tA, sA); sP *= tP; }
  }

  // exclusive (lanes above), apply incoming tile carry tc
  float eA = __shfl_down(sA, 1);
  float eP = __shfl_down(sP, 1);
  if (lane == 63) { eA = 0.f; eP = 1.f; }
  const float carry = fmaf(eP, tc, eA);

  // whole-tile composite (lane 0 inclusive) -> carry for next tile leftward
  const float gA = __shfl(sA, 0);
  const float gP = __shfl(sP, 0);
  tc = fmaf(gP, tc, gA);

  // fixup, stats, 4x f4 stores (lane stride 64B; 4 instrs cover the 4KB tile)
  float fs = 0.f, fq = 0.f;
  f4* go = (f4*)dst + 4 * lane;
#pragma unroll
  for (int q = 0; q < 4; ++q) {
    const float r0 = fmaf(cv[4 * q + 0], carry, rv[4 * q + 0]);
    const float r1 = fmaf(cv[4 * q + 1], carry, rv[4 * q + 1]);
    const float r2 = fmaf(cv[4 * q + 2], carry, rv[4 * q + 2]);
    const float r3 = fmaf(cv[4 * q + 3], carry, rv[4 * q + 3]);
    f4 o; o.x = r0; o.y = r1; o.z = r2; o.w = r3;
    go[q] = o;
    fs += (r0 + r1) + (r2 + r3);
    fq = fmaf(r0, r0, fmaf(r1, r1, fmaf(r2, r2, fmaf(r3, r3, fq))));
  }
  accS += (double)fs;
  accQ += (double)fq;
}

// ---------------------------------------------------------------------------
// K1: one ROW PER WAVE, zero barriers, zero LDS. 8 independent loads per tile
// (8-deep MLP at worst even if the compiler sinks them); double-buffered named
// A/B tile buffers with sched_barrier(0) pins (rules #18/#20).
// ---------------------------------------------------------------------------
__global__ __launch_bounds__(NT, 4) void er_scan(const float* __restrict__ rew,
                                                 const float* __restrict__ don,
                                                 float* __restrict__ out,
                                                 double* __restrict__ rowSum,
                                                 float* __restrict__ rowInv) {
  const int tid  = threadIdx.x;
  const int lane = tid & 63;
  const int wv   = tid >> 6;
  const int row  = blockIdx.x * WPB + wv;
  const size_t rbase = (size_t)row * TLEN;

  const f4* gr = (const f4*)(rew + rbase);
  const f4* gd = (const f4*)(don + rbase);
  float* ob = out + rbase;

  f4 aR[4], aD[4], bR[4], bD[4];

  // prologue: tile NTW-1 -> A   (tile k f4-base = k*(TPW/4); lane base 4*lane)
  {
    const int f = (NTW - 1) * (TPW / 4) + 4 * lane;
#pragma unroll
    for (int q = 0; q < 4; ++q) { aR[q] = gr[f + q]; aD[q] = gd[f + q]; }
  }

  double accS = 0.0, accQ = 0.0;
  float  tc = 0.f;

#pragma unroll
  for (int kb = NTW - 1; kb >= 1; kb -= 2) {
    // issue tile kb-1 -> B, consume tile kb from A
    {
      const int f = (kb - 1) * (TPW / 4) + 4 * lane;
#pragma unroll
      for (int q = 0; q < 4; ++q) { bR[q] = gr[f + q]; bD[q] = gd[f + q]; }
    }
    __builtin_amdgcn_sched_barrier(0);
    scan_tile16(aR, aD, lane, tc, ob + (size_t)kb * TPW, accS, accQ);

    // issue tile kb-2 -> A, consume tile kb-1 from B
    if (kb - 2 >= 0) {
      const int f = (kb - 2) * (TPW / 4) + 4 * lane;
#pragma unroll
      for (int q = 0; q < 4; ++q) { aR[q] = gr[f + q]; aD[q] = gd[f + q]; }
    }
    __builtin_amdgcn_sched_barrier(0);
    scan_tile16(bR, bD, lane, tc, ob + (size_t)(kb - 1) * TPW, accS, accQ);
  }

  // --- per-wave (per-row) stats reduction; no cross-wave communication ---
  double ds = accS, dq = accQ;
#pragma unroll
  for (int d = 32; d >= 1; d >>= 1) {
    ds += __shfl_down(ds, d);
    dq += __shfl_down(dq, d);
  }
  if (lane == 0) {
    rowSum[row] = ds;
    double var = (dq - ds * ds / (double)TLEN) / (double)(TLEN - 1);
    if (var < 0.0) var = 0.0;
    rowInv[row] = (float)(1.0 / (sqrt(var) + EPSN));
  }
}

// ---------------------------------------------------------------------------
// K2: reduce 4096 per-row sums -> global mean (single block)
// ---------------------------------------------------------------------------
__global__ __launch_bounds__(256) void er_mean(const double* __restrict__ rowSum,
                                               float* __restrict__ meanPtr) {
  const int tid = threadIdx.x;
  double s = 0.0;
  for (int i = tid; i < BROWS; i += 256) s += rowSum[i];
#pragma unroll
  for (int d = 32; d >= 1; d >>= 1) s += __shfl_down(s, d);
  __shared__ double red[4];
  const int lane = tid & 63, wv = tid >> 6;
  if (lane == 0) red[wv] = s;
  __syncthreads();
  if (tid == 0) {
    const double t = red[0] + red[1] + red[2] + red[3];
    *meanPtr = (float)(t / ((double)BROWS * (double)TLEN));
  }
}

// ---------------------------------------------------------------------------
// K3: out = (out - mean) * invstd[row]; per-row blocks (~4.6 TB/s measured)
// ---------------------------------------------------------------------------
__global__ __launch_bounds__(256) void er_norm(float* __restrict__ out,
                                               const float* __restrict__ rowInv,
                                               const float* __restrict__ meanPtr) {
  const int row = blockIdx.x;
  const float mean = *meanPtr;
  const float inv  = rowInv[row];
  f4* o4 = (f4*)(out + (size_t)row * TLEN);
#pragma unroll
  for (int i = threadIdx.x; i < TLEN / 4; i += 256) {
    f4 v = o4[i];
    v.x = (v.x - mean) * inv;
    v.y = (v.y - mean) * inv;
    v.z = (v.z - mean) * inv;
    v.w = (v.w - mean) * inv;
    o4[i] = v;
  }
}

extern "C" void kernel_launch(void* const* d_in, const int* in_sizes, int n_in,
                              void* d_out, int out_size, void* d_ws, size_t ws_size,
                              hipStream_t stream) {
  const float* rew = (const float*)d_in[0];
  const float* don = (const float*)d_in[1];
  float* out = (float*)d_out;

  double* rowSum  = (double*)d_ws;
  float*  rowInv  = (float*)((char*)d_ws + BROWS * 8);
  float*  meanPtr = (float*)((char*)d_ws + BROWS * 8 + BROWS * 4);

  er_scan<<<GRID, NT, 0, stream>>>(rew, don, out, rowSum, rowInv);
  er_mean<<<1, 256, 0, stream>>>(rowSum, meanPtr);
  er_norm<<<BROWS, 256, 0, stream>>>(out, rowInv, meanPtr);
}